// Round 13
// baseline (110.343 us; speedup 1.0000x reference)
//
#include <hip/hip_runtime.h>

// DynamicMemoryCell: B=8, N=2048, IN=256, MEM=256, CTX=128
// out0 = new_memory [8,2048,256] f32 ; out1 = attention_probs [8,2048,2048] f32
// Wv/value/context dead in reference -> skipped.
//
// R12: 6 launches -> 3. Launch1 = [k2ru || k1] fat kernel; Launch2 = [k3a || k2c];
// Launch3 = k3b. k0 deleted -- each wave converts its own fp32 weight cols to
// fp16 (hi/lo for Wq/Wk) in registers. Kernel bodies otherwise identical to R11.

typedef _Float16 half8 __attribute__((ext_vector_type(8)));
typedef _Float16 half4 __attribute__((ext_vector_type(4)));
typedef float floatx4 __attribute__((ext_vector_type(4)));

#define MFMA16(a, b, c) __builtin_amdgcn_mfma_f32_16x16x32_f16((a), (b), (c), 0, 0, 0)

// ws layout (units: _Float16). Only Q, K live in ws now; part aliases the front.
#define OFF_Q   524288
#define OFF_K   2621440
// part: f32[8][4][2048] = 256 KB at ws byte 0 (no overlap with OFF_Q at byte 1 MB).

__device__ __forceinline__ void gload16(const void* g, void* l) {
  __builtin_amdgcn_global_load_lds((const __attribute__((address_space(1))) unsigned int*)g,
                                   (__attribute__((address_space(3))) unsigned int*)l, 16, 0, 0);
}

// ---------------------------------------------------------------- Launch 1: [k2ru || k1]
// bx < 512 : k2ru role  (128 row-blocks x 4 col-groups; waves 0-3 r, 4-7 u)
// bx >= 512: k1 role    (256 row-blocks x {Q,K}; 8 waves x 16 cols, W hi/lo in regs)
__global__ __launch_bounds__(512, 4) void kA(
    const float* __restrict__ input, const float* __restrict__ prev,
    const float* __restrict__ Wq, const float* __restrict__ bq,
    const float* __restrict__ Wk, const float* __restrict__ bk,
    const float* __restrict__ Wr, const float* __restrict__ br,
    const float* __restrict__ Wu, const float* __restrict__ bu,
    _Float16* __restrict__ ws,
    _Float16* __restrict__ t_sc, _Float16* __restrict__ u_sc)
{
  __shared__ char smem[32768];
  const int tid = threadIdx.x, w = tid >> 6, l = tid & 63;
  const int lr = l & 15, lg = l >> 4;

  if (blockIdx.x < 512) {
    // ================= k2ru role =================
    const int b2 = blockIdx.x;
    const int rows0 = (b2 & 127) * 128;
    const int isU = w >> 2;
    const int c = (b2 >> 7) * 64 + (w & 3) * 16 + lr;

    const float* Wf = isU ? Wu : Wr;      // fp32 [256][512]
    half8 bw[16];
#pragma unroll
    for (int ks = 0; ks < 16; ++ks) {
      floatx4 w0 = *(const floatx4*)(Wf + (size_t)c * 512 + ks * 32 + lg * 8);
      floatx4 w1 = *(const floatx4*)(Wf + (size_t)c * 512 + ks * 32 + lg * 8 + 4);
      half8 h;
#pragma unroll
      for (int j = 0; j < 4; ++j) { h[j] = (_Float16)w0[j]; h[4 + j] = (_Float16)w1[j]; }
      bw[ks] = h;
    }
    const float bv = (isU ? bu : br)[c];

    const int srow = tid >> 5, scol = (tid & 31) * 8;
    const int ssz = (srow & 7) << 4;
    floatx4 sI0, sI1, sP0, sP1;

#define K2RU_LOAD(ch) { \
  const float* si = input + ((size_t)rows0 + (ch) * 16 + srow) * 256 + scol; \
  const float* sp = prev  + ((size_t)rows0 + (ch) * 16 + srow) * 256 + scol; \
  sI0 = *(const floatx4*)si; sI1 = *(const floatx4*)(si + 4); \
  sP0 = *(const floatx4*)sp; sP1 = *(const floatx4*)(sp + 4); }
#define K2RU_WRITE(ch) { char* bufw = smem + ((ch) & 1) * 16384; \
  half8 hi, hp; \
  _Pragma("unroll") for (int j = 0; j < 4; ++j) { \
    hi[j] = (_Float16)sI0[j]; hi[4+j] = (_Float16)sI1[j]; \
    hp[j] = (_Float16)sP0[j]; hp[4+j] = (_Float16)sP1[j]; } \
  int o = srow * 1024 + ((scol * 2) ^ ssz); \
  *(half8*)(bufw + o) = hi; *(half8*)(bufw + o + 512) = hp; }

    K2RU_LOAD(0); K2RU_WRITE(0);
    __syncthreads();
#pragma unroll 1
    for (int ch = 0; ch < 8; ++ch) {
      if (ch < 7) K2RU_LOAD(ch + 1);
      const char* buf = smem + (ch & 1) * 16384;
      floatx4 acc = {0.f, 0.f, 0.f, 0.f};
      const int base = lr * 1024, sz = (lr & 7) << 4;
#pragma unroll
      for (int ks = 0; ks < 16; ++ks) {   // ks>=8 = prev half
        half8 a = *(const half8*)(buf + base + ((ks * 64 + lg * 16) ^ sz));
        acc = MFMA16(a, bw[ks], acc);
      }
#pragma unroll
      for (int j = 0; j < 4; ++j) {
        const int crow = lg * 4 + j;
        const size_t grow = (size_t)rows0 + ch * 16 + crow;
        float g = 1.f / (1.f + __expf(-(acc[j] + bv)));
        if (!isU) {
          float m = (float)*(const _Float16*)(buf + crow * 1024 + 512 + ((c * 2) ^ ((crow & 7) << 4)));
          t_sc[grow * 256 + c] = (_Float16)(g * m);
        } else {
          u_sc[grow * 256 + c] = (_Float16)g;
        }
      }
      if (ch < 7) K2RU_WRITE(ch + 1);
      __syncthreads();
    }
  } else {
    // ================= k1 role =================
    const int b1 = blockIdx.x - 512;
    const int which = b1 >> 8;
    const int rows0 = (b1 & 255) * 64;
    const float* x = which ? prev : input;
    const float* Wf = which ? Wk : Wq;    // fp32 [128][256]
    const float* bias = which ? bk : bq;
    _Float16* out = ws + (which ? OFF_K : OFF_Q);
    const int c = w * 16 + lr;

    half8 bh[8], blo[8];
#pragma unroll
    for (int ks = 0; ks < 8; ++ks) {
      floatx4 w0 = *(const floatx4*)(Wf + (size_t)c * 256 + ks * 32 + lg * 8);
      floatx4 w1 = *(const floatx4*)(Wf + (size_t)c * 256 + ks * 32 + lg * 8 + 4);
      half8 h, lo;
#pragma unroll
      for (int j = 0; j < 4; ++j) {
        _Float16 h0 = (_Float16)w0[j];
        h[j] = h0; lo[j] = (_Float16)(w0[j] - (float)h0);
        _Float16 h1 = (_Float16)w1[j];
        h[4 + j] = h1; lo[4 + j] = (_Float16)(w1[j] - (float)h1);
      }
      bh[ks] = h; blo[ks] = lo;
    }
    const float bv = bias[c];

    const int srow = tid >> 5, scol = (tid & 31) * 8;
    const int ssz = (srow & 7) << 4;
    floatx4 st0, st1;

#define K1_LOAD(ch) { const float* src = x + ((size_t)rows0 + (ch) * 16 + srow) * 256 + scol; \
  st0 = *(const floatx4*)src; st1 = *(const floatx4*)(src + 4); }
#define K1_WRITE(ch) { char* bufw = smem + ((ch) & 1) * 8192; \
  half8 h; \
  _Pragma("unroll") for (int j = 0; j < 4; ++j) { \
    h[j] = (_Float16)st0[j]; h[4+j] = (_Float16)st1[j]; } \
  *(half8*)(bufw + srow * 512 + ((scol * 2) ^ ssz)) = h; }

    K1_LOAD(0); K1_WRITE(0);
    __syncthreads();
#pragma unroll 1
    for (int ch = 0; ch < 4; ++ch) {
      if (ch < 3) K1_LOAD(ch + 1);
      const char* buf = smem + (ch & 1) * 8192;
      floatx4 acc = {0.f, 0.f, 0.f, 0.f};
      const int base = lr * 512, sz = (lr & 7) << 4;
#pragma unroll
      for (int ks = 0; ks < 8; ++ks) {
        half8 ah = *(const half8*)(buf + base + ((ks * 64 + lg * 16) ^ sz));
        acc = MFMA16(ah, bh[ks], acc);
        acc = MFMA16(ah, blo[ks], acc);
      }
#pragma unroll
      for (int j = 0; j < 4; ++j)
        out[((size_t)rows0 + ch * 16 + lg * 4 + j) * 128 + c] = (_Float16)(acc[j] + bv);
      if (ch < 3) K1_WRITE(ch + 1);
      __syncthreads();
    }
  }
}

// ---------------------------------------------------------------- K3 staging macro
// Chunk = 128 keys x 256 B = 32 KB. LDS dest linear (gload_lds); global source
// pre-swizzled with col ^ ((row&7)<<4) so swizzled ds_read is conflict-free.
#define K3_STAGE(Kg, dst, ch) { \
  const char* g_ = (Kg) + (ch) * 32768; \
  _Pragma("unroll") for (int i_ = 0; i_ < 4; ++i_) { \
    int o_ = w * 1024 + i_ * 8192 + l * 16; \
    int row_ = o_ >> 8, col_ = o_ & 255; \
    gload16(g_ + row_ * 256 + (col_ ^ ((row_ & 7) << 4)), (dst) + w * 1024 + i_ * 8192); } }

// ---------------------------------------------------------------- Launch 2: [k3a || k2c]
// bx < 512 : k3a role (8 batches x 16 q-blocks x 4 key-quarters, row-sums -> part)
// bx >= 512: k2c role (256 row-blocks x 2 col-halves, candidate+combine -> out0)
__global__ __launch_bounds__(512, 4) void kB(
    const float* __restrict__ input, const float* __restrict__ prev,
    const float* __restrict__ Wc, const float* __restrict__ bc,
    const _Float16* __restrict__ ws, float* __restrict__ part,
    const _Float16* __restrict__ t_sc, const _Float16* __restrict__ u_sc,
    float* __restrict__ out0)
{
  __shared__ char smem[65536];
  const int tid = threadIdx.x, w = tid >> 6, l = tid & 63;
  const int lr = l & 15, lg = l >> 4;

  if (blockIdx.x < 512) {
    // ================= k3a role =================
    const int b3 = blockIdx.x;
    const int b = b3 & 7, q0 = ((b3 >> 3) & 15) * 128, kh = b3 >> 7;

    const _Float16* Q = ws + OFF_Q + ((size_t)b * 2048 + q0 + w * 16) * 128;
    const char* Kg = (const char*)(ws + OFF_K + ((size_t)b * 2048 + kh * 512) * 128);

    half8 qf[4];
#pragma unroll
    for (int ks = 0; ks < 4; ++ks)
      qf[ks] = *(const half8*)(Q + (size_t)lr * 128 + ks * 32 + lg * 8);

    char* kbuf0 = smem, * kbuf1 = smem + 32768;
    K3_STAGE(Kg, kbuf0, 0);
    __syncthreads();

    float se = 0.f;
#pragma unroll 1
    for (int ch = 0; ch < 4; ++ch) {
      if (ch < 3) K3_STAGE(Kg, ((ch + 1) & 1) ? kbuf1 : kbuf0, ch + 1);
      const char* buf = (ch & 1) ? kbuf1 : kbuf0;
#pragma unroll
      for (int kt = 0; kt < 8; ++kt) {
        const int kk = kt * 16 + lr;
        const int kbase = kk * 256, ksz = (kk & 7) << 4;
        half8 kf[4];
#pragma unroll
        for (int ks = 0; ks < 4; ++ks)
          kf[ks] = *(const half8*)(buf + kbase + ((ks * 64 + lg * 16) ^ ksz));
        floatx4 acc = {0.f, 0.f, 0.f, 0.f};
#pragma unroll
        for (int ks = 0; ks < 4; ++ks) acc = MFMA16(kf[ks], qf[ks], acc);
#pragma unroll
        for (int j = 0; j < 4; ++j) se += __expf(acc[j] - 14.f);
      }
      __syncthreads();
    }
    se += __shfl_xor(se, 16);
    se += __shfl_xor(se, 32);
    if (lg == 0)
      part[((size_t)b * 4 + kh) * 2048 + q0 + w * 16 + lr] = se;
  } else {
    // ================= k2c role =================
    const int b2 = blockIdx.x - 512;
    const int rows0 = (b2 & 255) * 64;
    const int c = (b2 >> 8) * 128 + w * 16 + lr;

    half8 bw[16];
#pragma unroll
    for (int ks = 0; ks < 16; ++ks) {
      floatx4 w0 = *(const floatx4*)(Wc + (size_t)c * 512 + ks * 32 + lg * 8);
      floatx4 w1 = *(const floatx4*)(Wc + (size_t)c * 512 + ks * 32 + lg * 8 + 4);
      half8 h;
#pragma unroll
      for (int j = 0; j < 4; ++j) { h[j] = (_Float16)w0[j]; h[4 + j] = (_Float16)w1[j]; }
      bw[ks] = h;
    }
    const float bv = bc[c];

    const int srow = tid >> 5, scol = (tid & 31) * 8;
    const int ssz = (srow & 7) << 4;
    floatx4 sI0, sI1;
    half8 sT;

#define K2C_LOAD(ch) { \
  const float* si = input + ((size_t)rows0 + (ch) * 16 + srow) * 256 + scol; \
  sI0 = *(const floatx4*)si; sI1 = *(const floatx4*)(si + 4); \
  sT = *(const half8*)(t_sc + ((size_t)rows0 + (ch) * 16 + srow) * 256 + scol); }
#define K2C_WRITE(ch) { char* bufw = smem + ((ch) & 1) * 16384; \
  half8 hi; \
  _Pragma("unroll") for (int j = 0; j < 4; ++j) { hi[j] = (_Float16)sI0[j]; hi[4+j] = (_Float16)sI1[j]; } \
  int o = srow * 1024 + ((scol * 2) ^ ssz); \
  *(half8*)(bufw + o) = hi; *(half8*)(bufw + o + 512) = sT; }

    K2C_LOAD(0); K2C_WRITE(0);
    __syncthreads();
#pragma unroll 1
    for (int ch = 0; ch < 4; ++ch) {
      if (ch < 3) K2C_LOAD(ch + 1);
      const char* buf = smem + (ch & 1) * 16384;
      floatx4 acc = {0.f, 0.f, 0.f, 0.f};
      const int base = lr * 1024, sz = (lr & 7) << 4;
#pragma unroll
      for (int ks = 0; ks < 16; ++ks) {   // ks>=8 = t half
        half8 a = *(const half8*)(buf + base + ((ks * 64 + lg * 16) ^ sz));
        acc = MFMA16(a, bw[ks], acc);
      }
#pragma unroll
      for (int j = 0; j < 4; ++j) {
        const size_t grow = (size_t)rows0 + ch * 16 + lg * 4 + j;
        float e2 = __expf(2.f * (acc[j] + bv));
        float cg = (e2 - 1.f) / (e2 + 1.f);
        float u = (float)u_sc[grow * 256 + c];
        float m = prev[grow * 256 + c];
        out0[grow * 256 + c] = (1.f - u) * m + u * cg;
      }
      if (ch < 3) K2C_WRITE(ch + 1);
      __syncthreads();
    }
  }
}

// ---------------------------------------------------------------- Launch 3: k3b (recompute + normalize + store)
__global__ __launch_bounds__(512) void k3b_store(
    const _Float16* __restrict__ ws, const float* __restrict__ part,
    float* __restrict__ out1)
{
  __shared__ char kbuf[2][32768];
  const int b = blockIdx.x, q0 = blockIdx.y * 128, kh = blockIdx.z;
  const int tid = threadIdx.x, w = tid >> 6, l = tid & 63;
  const int lr = l & 15, lg = l >> 4;

  const int q = q0 + w * 16 + lr;
  const _Float16* Q = ws + OFF_Q + ((size_t)b * 2048 + q0 + w * 16) * 128;
  const char* Kg = (const char*)(ws + OFF_K + ((size_t)b * 2048 + kh * 512) * 128);

  half8 qf[4];
#pragma unroll
  for (int ks = 0; ks < 4; ++ks)
    qf[ks] = *(const half8*)(Q + (size_t)lr * 128 + ks * 32 + lg * 8);
  const float inv = 1.f / (part[(size_t)(b * 4 + 0) * 2048 + q] +
                           part[(size_t)(b * 4 + 1) * 2048 + q] +
                           part[(size_t)(b * 4 + 2) * 2048 + q] +
                           part[(size_t)(b * 4 + 3) * 2048 + q]);

  K3_STAGE(Kg, kbuf[0], 0);
  __syncthreads();

  float* orow = out1 + ((size_t)b * 2048 + q) * 2048 + kh * 512;
#pragma unroll 1
  for (int ch = 0; ch < 4; ++ch) {
    if (ch < 3) K3_STAGE(Kg, kbuf[(ch + 1) & 1], ch + 1);
    const char* buf = kbuf[ch & 1];
#pragma unroll
    for (int kt = 0; kt < 8; ++kt) {
      const int kk = kt * 16 + lr;
      const int kbase = kk * 256, ksz = (kk & 7) << 4;
      half8 kf[4];
#pragma unroll
      for (int ks = 0; ks < 4; ++ks)
        kf[ks] = *(const half8*)(buf + kbase + ((ks * 64 + lg * 16) ^ ksz));
      floatx4 acc = {0.f, 0.f, 0.f, 0.f};
#pragma unroll
      for (int ks = 0; ks < 4; ++ks) acc = MFMA16(kf[ks], qf[ks], acc);
      floatx4 v;
#pragma unroll
      for (int j = 0; j < 4; ++j) v[j] = __expf(acc[j] - 14.f) * inv;
      *(floatx4*)(orow + ch * 128 + kt * 16 + lg * 4) = v;
    }
    __syncthreads();
  }
}

// ----------------------------------------------------------------
extern "C" void kernel_launch(void* const* d_in, const int* in_sizes, int n_in,
                              void* d_out, int out_size, void* d_ws, size_t ws_size,
                              hipStream_t stream)
{
  const float* input = (const float*)d_in[0];
  const float* prev  = (const float*)d_in[1];
  const float* Wq = (const float*)d_in[2];
  const float* bq = (const float*)d_in[3];
  const float* Wk = (const float*)d_in[4];
  const float* bk = (const float*)d_in[5];
  const float* Wu = (const float*)d_in[8];
  const float* bu = (const float*)d_in[9];
  const float* Wr = (const float*)d_in[10];
  const float* br = (const float*)d_in[11];
  const float* Wc = (const float*)d_in[12];
  const float* bc = (const float*)d_in[13];

  float* out0 = (float*)d_out;                        // new_memory [8,2048,256]
  float* out1 = out0 + (size_t)8 * 2048 * 256;        // attention_probs [8,2048,2048]
  _Float16* ws = (_Float16*)d_ws;                     // 9,437,184 bytes used

  // t/u intermediates live in the out1 region (k3b overwrites it afterwards)
  _Float16* t_sc = (_Float16*)out1;                   // 4.19M halves
  _Float16* u_sc = (_Float16*)out1 + 4194304;         // 4.19M halves
  // softmax partials at ws front (weights no longer staged in ws): 256 KB
  float* part = (float*)ws;

  hipLaunchKernelGGL(kA, dim3(1024), dim3(512), 0, stream,
                     input, prev, Wq, bq, Wk, bk, Wr, br, Wu, bu, ws, t_sc, u_sc);
  hipLaunchKernelGGL(kB, dim3(1024), dim3(512), 0, stream,
                     input, prev, Wc, bc, ws, part, t_sc, u_sc, out0);
  hipLaunchKernelGGL(k3b_store, dim3(8, 16, 4), dim3(512), 0, stream, ws, part, out1);
}